// Round 1
// baseline (744.988 us; speedup 1.0000x reference)
//
#include <hip/hip_runtime.h>

#define NPTS 4096
#define CH 64
#define BATCH 8
#define KNN 20
#define NEG_SLOPE 0.2f
#define EPSV 1e-5f
#define NEG_INF (-3.4e38f)

// ---------------- K0: xx[b,n] = sum_c x[b,c,n]^2 ----------------
__global__ void k_xx(const float* __restrict__ x, float* __restrict__ xx) {
  int t = blockIdx.x * 256 + threadIdx.x;          // [0, B*N)
  int b = t >> 12, n = t & (NPTS - 1);
  const float* xp = x + ((size_t)b * CH * NPTS) + n;
  float s = 0.f;
#pragma unroll
  for (int c = 0; c < CH; ++c) { float v = xp[(size_t)c * NPTS]; s = fmaf(v, v, s); }
  xx[t] = s;
}

// ---------------- K2: P'[t,o], Q'[t,o] ----------------
__global__ void k_pq(const float* __restrict__ x, const float* __restrict__ W,
                     const float* __restrict__ gamma, const float* __restrict__ beta,
                     const float* __restrict__ rmean, const float* __restrict__ rvar,
                     float* __restrict__ P, float* __restrict__ Q) {
  __shared__ float Ws1[CH * CH];   // [c][o], W1*inv
  __shared__ float Wsd[CH * CH];   // [c][o], (W2-W1)*inv
  int tid = threadIdx.x;
  for (int i = tid; i < CH * CH; i += 256) {
    int o = i & 63, c = i >> 6;
    float s = gamma[o] * rsqrtf(rvar[o] + EPSV);
    float w1 = W[o * 128 + c], w2 = W[o * 128 + 64 + c];
    Ws1[c * 64 + o] = w1 * s;
    Wsd[c * 64 + o] = (w2 - w1) * s;
  }
  __syncthreads();
  int o = tid & 63, ng = tid >> 6;
  float s = gamma[o] * rsqrtf(rvar[o] + EPSV);
  float shift = beta[o] - rmean[o] * s;
  int base = blockIdx.x * 16;
  for (int rp = 0; rp < 4; ++rp) {
    int t = base + rp * 4 + ng;                    // row in [0, B*N)
    int b = t >> 12, n = t & (NPTS - 1);
    const float* xp = x + ((size_t)b * CH * NPTS) + n;
    float accp = 0.f, accq = 0.f;
#pragma unroll 8
    for (int c = 0; c < CH; ++c) {
      float xv = xp[(size_t)c * NPTS];
      accp = fmaf(xv, Ws1[c * 64 + o], accp);
      accq = fmaf(xv, Wsd[c * 64 + o], accq);
    }
    P[(size_t)t * 64 + o] = accp;
    Q[(size_t)t * 64 + o] = accq + shift;
  }
}

// ---------------- K1: fused distance-GEMM + register-direct top-20 ----------
// RESTRUCTURED vs prior round:
//  * wave w owns rows 16w..16w+15; lane owns cols (lane, 64+lane) of the
//    128-wide tile -> per-thread acc = 16x2. Selection consumes acc REGISTERS
//    directly: the Ds LDS round-trip (write+read+its 1.26e7 bank-conflict
//    cycles) is eliminated.
//  * A-fragment reads become wave-uniform (broadcast ds_read_b128, ~free);
//    B reads are two conflict-free b32 (fusable ds_read2_b32).
//  * B-tile double-buffered in LDS (As 16KB + 2x32KB = 80KB -> 2 blocks/CU,
//    which the 512-block grid caps anyway); next tile prefetched to registers
//    right after the barrier (issue-early/write-late) -> ONE barrier per tile
//    instead of four.
//  * fp math: each acc element accumulates c=0..63 with the same fmaf chain,
//    d = (2f*acc - xnr) - xmv identical, selection order (g=0 cols ascending,
//    then g=1) identical -> indices bit-identical to prior passing kernel.
__launch_bounds__(256, 2)
__global__ void k_knn(const float* __restrict__ x, const float* __restrict__ xx,
                      int* __restrict__ idxout) {
  __shared__ float As[64 * 64];         // 16 KB, [c][n]
  __shared__ float Bs[2][64 * 128];     // 64 KB, [buf][c][m]
  int tid = threadIdx.x;
  int nb = blockIdx.x, b = blockIdx.y;
  int n0 = nb * 64;
  const float* xb = x + (size_t)b * CH * NPTS;
  const float* xxb = xx + b * NPTS;
  int lane = tid & 63;
  int w = tid >> 6;

  // ---- stage A-tile (64 ch x 64 rows), once ----
#pragma unroll
  for (int k = 0; k < 4; ++k) {
    int chunk = tid + 256 * k;                     // 0..1023
    int c = chunk >> 4, cn = (chunk & 15) << 2;
    *(float4*)(As + c * 64 + cn) = *(const float4*)(xb + (size_t)c * NPTS + n0 + cn);
  }

  // ---- prologue: stage B tile 0 into buf 0 ----
#pragma unroll
  for (int k = 0; k < 8; ++k) {
    int chunk = tid + 256 * k;                     // 0..2047
    int c = chunk >> 5, cm = (chunk & 31) << 2;
    *(float4*)(&Bs[0][c * 128 + cm]) = *(const float4*)(xb + (size_t)c * NPTS + cm);
  }

  // per-row xx for this wave's 16 rows (wave-uniform values)
  float xnr[16];
#pragma unroll
  for (int r = 0; r < 16; ++r) xnr[r] = xxb[n0 + 16 * w + r];

  // distributed top lists: lane l holds the (l+1)-th best of row 16w+r
  float val[16]; int idx[16];
#pragma unroll
  for (int r = 0; r < 16; ++r) { val[r] = NEG_INF; idx[r] = 0; }

  __syncthreads();

  int cur = 0;
  for (int mt = 0; mt < NPTS / 128; ++mt) {
    int m0 = mt * 128;

    // prefetch next B-tile to registers (latency hides under GEMM)
    float4 rb[8];
    if (mt < NPTS / 128 - 1) {
#pragma unroll
      for (int k = 0; k < 8; ++k) {
        int chunk = tid + 256 * k;
        int c = chunk >> 5, cm = (chunk & 31) << 2;
        rb[k] = *(const float4*)(xb + (size_t)c * NPTS + (m0 + 128) + cm);
      }
    }
    float xm0 = xxb[m0 + lane];
    float xm1 = xxb[m0 + 64 + lane];

    const float* Bc = Bs[cur];
    const float* Aw = As + 16 * w;

    float acc0[16], acc1[16];
#pragma unroll
    for (int r = 0; r < 16; ++r) { acc0[r] = 0.f; acc1[r] = 0.f; }

#pragma unroll 4
    for (int c = 0; c < CH; ++c) {                 // same fp op order per element
      float4 A0 = *(const float4*)(Aw + c * 64);
      float4 A1 = *(const float4*)(Aw + c * 64 + 4);
      float4 A2 = *(const float4*)(Aw + c * 64 + 8);
      float4 A3 = *(const float4*)(Aw + c * 64 + 12);
      float b0 = Bc[c * 128 + lane];
      float b1 = Bc[c * 128 + 64 + lane];
      acc0[0]  = fmaf(A0.x, b0, acc0[0]);   acc1[0]  = fmaf(A0.x, b1, acc1[0]);
      acc0[1]  = fmaf(A0.y, b0, acc0[1]);   acc1[1]  = fmaf(A0.y, b1, acc1[1]);
      acc0[2]  = fmaf(A0.z, b0, acc0[2]);   acc1[2]  = fmaf(A0.z, b1, acc1[2]);
      acc0[3]  = fmaf(A0.w, b0, acc0[3]);   acc1[3]  = fmaf(A0.w, b1, acc1[3]);
      acc0[4]  = fmaf(A1.x, b0, acc0[4]);   acc1[4]  = fmaf(A1.x, b1, acc1[4]);
      acc0[5]  = fmaf(A1.y, b0, acc0[5]);   acc1[5]  = fmaf(A1.y, b1, acc1[5]);
      acc0[6]  = fmaf(A1.z, b0, acc0[6]);   acc1[6]  = fmaf(A1.z, b1, acc1[6]);
      acc0[7]  = fmaf(A1.w, b0, acc0[7]);   acc1[7]  = fmaf(A1.w, b1, acc1[7]);
      acc0[8]  = fmaf(A2.x, b0, acc0[8]);   acc1[8]  = fmaf(A2.x, b1, acc1[8]);
      acc0[9]  = fmaf(A2.y, b0, acc0[9]);   acc1[9]  = fmaf(A2.y, b1, acc1[9]);
      acc0[10] = fmaf(A2.z, b0, acc0[10]);  acc1[10] = fmaf(A2.z, b1, acc1[10]);
      acc0[11] = fmaf(A2.w, b0, acc0[11]);  acc1[11] = fmaf(A2.w, b1, acc1[11]);
      acc0[12] = fmaf(A3.x, b0, acc0[12]);  acc1[12] = fmaf(A3.x, b1, acc1[12]);
      acc0[13] = fmaf(A3.y, b0, acc0[13]);  acc1[13] = fmaf(A3.y, b1, acc1[13]);
      acc0[14] = fmaf(A3.z, b0, acc0[14]);  acc1[14] = fmaf(A3.z, b1, acc1[14]);
      acc0[15] = fmaf(A3.w, b0, acc0[15]);  acc1[15] = fmaf(A3.w, b1, acc1[15]);
    }

    // selection straight from registers; lane == column within each 64-group.
    // g=0 (cols m0..m0+63) fully processed before g=1 -> stable ties, lowest
    // column first within a group via ctz. Identical semantics to prior kernel.
#pragma unroll
    for (int r = 0; r < 16; ++r) {
      {
        float d = (2.f * acc0[r] - xnr[r]) - xm0;
        float th = __shfl(val[r], KNN - 1);        // current 20th-best
        unsigned long long hit = __ballot(d > th);
        int mg = m0;
        while (hit) {
          int j = __builtin_ctzll(hit);
          hit &= hit - 1;
          float cv = __shfl(d, j);
          int cm = mg + j;
          unsigned long long km = __ballot(val[r] >= cv);  // equals stay above
          int cnt = __popcll(km);
          float sv = __shfl_up(val[r], 1);
          int si = __shfl_up(idx[r], 1);
          if (lane >= cnt) {
            val[r] = (lane == cnt) ? cv : sv;
            idx[r] = (lane == cnt) ? cm : si;
          }
        }
      }
      {
        float d = (2.f * acc1[r] - xnr[r]) - xm1;
        float th = __shfl(val[r], KNN - 1);
        unsigned long long hit = __ballot(d > th);
        int mg = m0 + 64;
        while (hit) {
          int j = __builtin_ctzll(hit);
          hit &= hit - 1;
          float cv = __shfl(d, j);
          int cm = mg + j;
          unsigned long long km = __ballot(val[r] >= cv);
          int cnt = __popcll(km);
          float sv = __shfl_up(val[r], 1);
          int si = __shfl_up(idx[r], 1);
          if (lane >= cnt) {
            val[r] = (lane == cnt) ? cv : sv;
            idx[r] = (lane == cnt) ? cm : si;
          }
        }
      }
    }

    // write prefetched tile into the other buffer; safe: all waves finished
    // reading it before the barrier that ended tile mt-1.
    if (mt < NPTS / 128 - 1) {
      float* Bn = Bs[cur ^ 1];
#pragma unroll
      for (int k = 0; k < 8; ++k) {
        int chunk = tid + 256 * k;
        int c = chunk >> 5, cm = (chunk & 31) << 2;
        *(float4*)(&Bn[c * 128 + cm]) = rb[k];
      }
    }
    __syncthreads();                               // ONE barrier per tile
    cur ^= 1;
  }

  // emit: lane l (<20) holds l-th best index for row 16w+r
#pragma unroll
  for (int r = 0; r < 16; ++r) {
    int n = n0 + 16 * w + r;
    if (lane < KNN) idxout[(size_t)(b * NPTS + n) * KNN + lane] = idx[r];
  }
}

// ---------------- K3: gather + max + leaky, transpose to (B,O,N) ----------------
__global__ void k_out(const float* __restrict__ P, const float* __restrict__ Q,
                      const int* __restrict__ idx, float* __restrict__ out) {
  __shared__ float T[64 * 65];
  int tid = threadIdx.x;
  int nb = blockIdx.x, b = blockIdx.y;
  int n0 = nb * 64;
  int o = tid & 63, ng = tid >> 6;
  const float* Pb = P + (size_t)b * NPTS * 64;
  for (int p = 0; p < 16; ++p) {
    int nl = p * 4 + ng;
    int n = n0 + nl;
    const int* ip = idx + (size_t)(b * NPTS + n) * KNN;
    float mx = NEG_INF;
#pragma unroll
    for (int k = 0; k < KNN; ++k) {
      int id = ip[k];
      float v = Pb[(size_t)id * 64 + o];
      mx = fmaxf(mx, v);
    }
    float z = mx + Q[(size_t)(b * NPTS + n) * 64 + o];
    z = (z >= 0.f) ? z : NEG_SLOPE * z;
    T[o * 65 + nl] = z;
  }
  __syncthreads();
  float* ob = out + (size_t)b * 64 * NPTS + n0;
  int nl = tid & 63;
  for (int w = 0; w < 16; ++w) {
    int oo = w * 4 + ng;
    ob[(size_t)oo * NPTS + nl] = T[oo * 65 + nl];
  }
}

extern "C" void kernel_launch(void* const* d_in, const int* in_sizes, int n_in,
                              void* d_out, int out_size, void* d_ws, size_t ws_size,
                              hipStream_t stream) {
  const float* x     = (const float*)d_in[0];
  const float* W     = (const float*)d_in[1];
  const float* gamma = (const float*)d_in[2];
  const float* beta  = (const float*)d_in[3];
  const float* rmean = (const float*)d_in[4];
  const float* rvar  = (const float*)d_in[5];
  float* out = (float*)d_out;

  float* xx = (float*)d_ws;                        // 32768 floats
  float* P  = xx + 32768;                          // 2097152 floats
  float* Q  = P + 2097152;                         // 2097152 floats
  int*   idx = (int*)(Q + 2097152);                // 655360 ints

  k_xx<<<BATCH * NPTS / 256, 256, 0, stream>>>(x, xx);
  k_pq<<<BATCH * NPTS / 16, 256, 0, stream>>>(x, W, gamma, beta, rmean, rvar, P, Q);
  k_knn<<<dim3(NPTS / 64, BATCH), 256, 0, stream>>>(x, xx, idx);
  k_out<<<dim3(NPTS / 64, BATCH), 256, 0, stream>>>(P, Q, idx, out);
}

// Round 2
// 725.021 us; speedup vs baseline: 1.0275x; 1.0275x over previous
//
#include <hip/hip_runtime.h>

#define NPTS 4096
#define CH 64
#define BATCH 8
#define KNN 20
#define NEG_SLOPE 0.2f
#define EPSV 1e-5f
#define NEG_INF (-3.4e38f)

// ---------------- K0: xx[b,n] = sum_c x[b,c,n]^2 ----------------
__global__ void k_xx(const float* __restrict__ x, float* __restrict__ xx) {
  int t = blockIdx.x * 256 + threadIdx.x;          // [0, B*N)
  int b = t >> 12, n = t & (NPTS - 1);
  const float* xp = x + ((size_t)b * CH * NPTS) + n;
  float s = 0.f;
#pragma unroll
  for (int c = 0; c < CH; ++c) { float v = xp[(size_t)c * NPTS]; s = fmaf(v, v, s); }
  xx[t] = s;
}

// ---------------- K2: P'[t,o], Q'[t,o] ----------------
__global__ void k_pq(const float* __restrict__ x, const float* __restrict__ W,
                     const float* __restrict__ gamma, const float* __restrict__ beta,
                     const float* __restrict__ rmean, const float* __restrict__ rvar,
                     float* __restrict__ P, float* __restrict__ Q) {
  __shared__ float Ws1[CH * CH];   // [c][o], W1*inv
  __shared__ float Wsd[CH * CH];   // [c][o], (W2-W1)*inv
  int tid = threadIdx.x;
  for (int i = tid; i < CH * CH; i += 256) {
    int o = i & 63, c = i >> 6;
    float s = gamma[o] * rsqrtf(rvar[o] + EPSV);
    float w1 = W[o * 128 + c], w2 = W[o * 128 + 64 + c];
    Ws1[c * 64 + o] = w1 * s;
    Wsd[c * 64 + o] = (w2 - w1) * s;
  }
  __syncthreads();
  int o = tid & 63, ng = tid >> 6;
  float s = gamma[o] * rsqrtf(rvar[o] + EPSV);
  float shift = beta[o] - rmean[o] * s;
  int base = blockIdx.x * 16;
  for (int rp = 0; rp < 4; ++rp) {
    int t = base + rp * 4 + ng;                    // row in [0, B*N)
    int b = t >> 12, n = t & (NPTS - 1);
    const float* xp = x + ((size_t)b * CH * NPTS) + n;
    float accp = 0.f, accq = 0.f;
#pragma unroll 8
    for (int c = 0; c < CH; ++c) {
      float xv = xp[(size_t)c * NPTS];
      accp = fmaf(xv, Ws1[c * 64 + o], accp);
      accq = fmaf(xv, Wsd[c * 64 + o], accq);
    }
    P[(size_t)t * 64 + o] = accp;
    Q[(size_t)t * 64 + o] = accq + shift;
  }
}

// ---------------- K1 helpers ----------------
// async global->LDS, 16B per lane. LDS dest is wave-uniform base + lane*16.
__device__ __forceinline__ void gload_lds16(const float* g, float* l) {
  __builtin_amdgcn_global_load_lds(
      (const __attribute__((address_space(1))) void*)g,
      (__attribute__((address_space(3))) void*)l, 16, 0, 0);
}

// stage one 64ch x 128col B-tile (32 KB) async. 32 chunks of 1 KB; wave w
// takes chunks w, w+4, ... Chunk q covers rows c=2q,2q+1 (128 floats each):
// lane l -> LDS float (q*256 + 4l) == row 2q+(l>>5), col 4*(l&31). Global
// source is per-lane; LDS base (Bdst + q*256) is wave-uniform. No VGPR
// round-trip -> no spillable live range.
__device__ __forceinline__ void stage_b(const float* xb, int mcol, float* Bdst,
                                        int w, int lane) {
#pragma unroll
  for (int k = 0; k < 8; ++k) {
    int q = w + 4 * k;
    int c = 2 * q + (lane >> 5);
    int cm = (lane & 31) << 2;
    gload_lds16(xb + (size_t)c * NPTS + mcol + cm, Bdst + q * 256);
  }
}

// GEMM (16 rows x 2 cols per thread, lane==col within each 64-group) +
// register-direct ballot top-k insert. fp op order identical to the passing
// kernels: acc chains c=0..63, d=(2f*acc - xnr) - xm, group 0 then group 1,
// ctz-ascending within a group -> indices bit-identical.
__device__ __forceinline__ void tile_work(const float* Bc, const float* As,
                                          const float* xxb, int m0, int w, int lane,
                                          const float (&xnr)[16],
                                          float (&val)[16], int (&idx)[16]) {
  float xm0 = xxb[m0 + lane];
  float xm1 = xxb[m0 + 64 + lane];
  const float* Aw = As + 16 * w;

  float acc0[16], acc1[16];
#pragma unroll
  for (int r = 0; r < 16; ++r) { acc0[r] = 0.f; acc1[r] = 0.f; }

#pragma unroll 4
  for (int c = 0; c < CH; ++c) {
    float4 A0 = *(const float4*)(Aw + c * 64);
    float4 A1 = *(const float4*)(Aw + c * 64 + 4);
    float4 A2 = *(const float4*)(Aw + c * 64 + 8);
    float4 A3 = *(const float4*)(Aw + c * 64 + 12);
    float b0 = Bc[c * 128 + lane];
    float b1 = Bc[c * 128 + 64 + lane];
    acc0[0]  = fmaf(A0.x, b0, acc0[0]);   acc1[0]  = fmaf(A0.x, b1, acc1[0]);
    acc0[1]  = fmaf(A0.y, b0, acc0[1]);   acc1[1]  = fmaf(A0.y, b1, acc1[1]);
    acc0[2]  = fmaf(A0.z, b0, acc0[2]);   acc1[2]  = fmaf(A0.z, b1, acc1[2]);
    acc0[3]  = fmaf(A0.w, b0, acc0[3]);   acc1[3]  = fmaf(A0.w, b1, acc1[3]);
    acc0[4]  = fmaf(A1.x, b0, acc0[4]);   acc1[4]  = fmaf(A1.x, b1, acc1[4]);
    acc0[5]  = fmaf(A1.y, b0, acc0[5]);   acc1[5]  = fmaf(A1.y, b1, acc1[5]);
    acc0[6]  = fmaf(A1.z, b0, acc0[6]);   acc1[6]  = fmaf(A1.z, b1, acc1[6]);
    acc0[7]  = fmaf(A1.w, b0, acc0[7]);   acc1[7]  = fmaf(A1.w, b1, acc1[7]);
    acc0[8]  = fmaf(A2.x, b0, acc0[8]);   acc1[8]  = fmaf(A2.x, b1, acc1[8]);
    acc0[9]  = fmaf(A2.y, b0, acc0[9]);   acc1[9]  = fmaf(A2.y, b1, acc1[9]);
    acc0[10] = fmaf(A2.z, b0, acc0[10]);  acc1[10] = fmaf(A2.z, b1, acc1[10]);
    acc0[11] = fmaf(A2.w, b0, acc0[11]);  acc1[11] = fmaf(A2.w, b1, acc1[11]);
    acc0[12] = fmaf(A3.x, b0, acc0[12]);  acc1[12] = fmaf(A3.x, b1, acc1[12]);
    acc0[13] = fmaf(A3.y, b0, acc0[13]);  acc1[13] = fmaf(A3.y, b1, acc1[13]);
    acc0[14] = fmaf(A3.z, b0, acc0[14]);  acc1[14] = fmaf(A3.z, b1, acc1[14]);
    acc0[15] = fmaf(A3.w, b0, acc0[15]);  acc1[15] = fmaf(A3.w, b1, acc1[15]);
  }

#pragma unroll
  for (int r = 0; r < 16; ++r) {
    {
      float d = (2.f * acc0[r] - xnr[r]) - xm0;
      float th = __shfl(val[r], KNN - 1);
      unsigned long long hit = __ballot(d > th);
      int mg = m0;
      while (hit) {
        int j = __builtin_ctzll(hit);
        hit &= hit - 1;
        float cv = __shfl(d, j);
        int cm = mg + j;
        unsigned long long km = __ballot(val[r] >= cv);
        int cnt = __popcll(km);
        float sv = __shfl_up(val[r], 1);
        int si = __shfl_up(idx[r], 1);
        if (lane >= cnt) {
          val[r] = (lane == cnt) ? cv : sv;
          idx[r] = (lane == cnt) ? cm : si;
        }
      }
    }
    {
      float d = (2.f * acc1[r] - xnr[r]) - xm1;
      float th = __shfl(val[r], KNN - 1);
      unsigned long long hit = __ballot(d > th);
      int mg = m0 + 64;
      while (hit) {
        int j = __builtin_ctzll(hit);
        hit &= hit - 1;
        float cv = __shfl(d, j);
        int cm = mg + j;
        unsigned long long km = __ballot(val[r] >= cv);
        int cnt = __popcll(km);
        float sv = __shfl_up(val[r], 1);
        int si = __shfl_up(idx[r], 1);
        if (lane >= cnt) {
          val[r] = (lane == cnt) ? cv : sv;
          idx[r] = (lane == cnt) ? cm : si;
        }
      }
    }
  }
}

// ---------------- K1: fused distance-GEMM + register-direct top-20 ----------
// LDS = As 16KB + B0 32KB + B1 32KB = 80KB -> 2 blocks/CU (= grid cap).
// B0/B1 are DISTINCT static arrays so the waitcnt pass can disambiguate the
// async prefetch (writes B_next) from the GEMM ds_reads (B_cur).
// One __syncthreads per tile: its vmcnt(0) drain retires the async stage
// issued a full GEMM+selection earlier.
__launch_bounds__(256, 2)
__global__ void k_knn(const float* __restrict__ x, const float* __restrict__ xx,
                      int* __restrict__ idxout) {
  __shared__ float As[64 * 64];
  __shared__ float B0[64 * 128];
  __shared__ float B1[64 * 128];
  int tid = threadIdx.x;
  int nb = blockIdx.x, b = blockIdx.y;
  int n0 = nb * 64;
  const float* xb = x + (size_t)b * CH * NPTS;
  const float* xxb = xx + b * NPTS;
  int lane = tid & 63;
  int w = tid >> 6;

  // issue async stage of B tile 0 first (overlaps A staging)
  stage_b(xb, 0, B0, w, lane);

  // stage A-tile (64 ch x 64 rows)
#pragma unroll
  for (int k = 0; k < 4; ++k) {
    int chunk = tid + 256 * k;                     // 0..1023
    int c = chunk >> 4, cn = (chunk & 15) << 2;
    *(float4*)(As + c * 64 + cn) = *(const float4*)(xb + (size_t)c * NPTS + n0 + cn);
  }

  float xnr[16];
#pragma unroll
  for (int r = 0; r < 16; ++r) xnr[r] = xxb[n0 + 16 * w + r];

  float val[16]; int idx[16];
#pragma unroll
  for (int r = 0; r < 16; ++r) { val[r] = NEG_INF; idx[r] = 0; }

  __syncthreads();                                 // drains vmcnt: B0 + As ready

#pragma unroll 1
  for (int mt = 0; mt < NPTS / 128; mt += 2) {
    // prefetch tile mt+1 -> B1 (B1's readers finished before last barrier)
    stage_b(xb, (mt + 1) * 128, B1, w, lane);
    tile_work(B0, As, xxb, mt * 128, w, lane, xnr, val, idx);
    __syncthreads();                               // B1 staged; B0 readers done

    if (mt + 2 < NPTS / 128)
      stage_b(xb, (mt + 2) * 128, B0, w, lane);    // prefetch tile mt+2 -> B0
    tile_work(B1, As, xxb, (mt + 1) * 128, w, lane, xnr, val, idx);
    __syncthreads();                               // B0 staged; B1 readers done
  }

  // emit: lane l (<20) holds l-th best index for row 16w+r
#pragma unroll
  for (int r = 0; r < 16; ++r) {
    int n = n0 + 16 * w + r;
    if (lane < KNN) idxout[(size_t)(b * NPTS + n) * KNN + lane] = idx[r];
  }
}

// ---------------- K3: gather + max + leaky, transpose to (B,O,N) ----------------
__global__ void k_out(const float* __restrict__ P, const float* __restrict__ Q,
                      const int* __restrict__ idx, float* __restrict__ out) {
  __shared__ float T[64 * 65];
  int tid = threadIdx.x;
  int nb = blockIdx.x, b = blockIdx.y;
  int n0 = nb * 64;
  int o = tid & 63, ng = tid >> 6;
  const float* Pb = P + (size_t)b * NPTS * 64;
  for (int p = 0; p < 16; ++p) {
    int nl = p * 4 + ng;
    int n = n0 + nl;
    const int* ip = idx + (size_t)(b * NPTS + n) * KNN;
    float mx = NEG_INF;
#pragma unroll
    for (int k = 0; k < KNN; ++k) {
      int id = ip[k];
      float v = Pb[(size_t)id * 64 + o];
      mx = fmaxf(mx, v);
    }
    float z = mx + Q[(size_t)(b * NPTS + n) * 64 + o];
    z = (z >= 0.f) ? z : NEG_SLOPE * z;
    T[o * 65 + nl] = z;
  }
  __syncthreads();
  float* ob = out + (size_t)b * 64 * NPTS + n0;
  int nl = tid & 63;
  for (int w = 0; w < 16; ++w) {
    int oo = w * 4 + ng;
    ob[(size_t)oo * NPTS + nl] = T[oo * 65 + nl];
  }
}

extern "C" void kernel_launch(void* const* d_in, const int* in_sizes, int n_in,
                              void* d_out, int out_size, void* d_ws, size_t ws_size,
                              hipStream_t stream) {
  const float* x     = (const float*)d_in[0];
  const float* W     = (const float*)d_in[1];
  const float* gamma = (const float*)d_in[2];
  const float* beta  = (const float*)d_in[3];
  const float* rmean = (const float*)d_in[4];
  const float* rvar  = (const float*)d_in[5];
  float* out = (float*)d_out;

  float* xx = (float*)d_ws;                        // 32768 floats
  float* P  = xx + 32768;                          // 2097152 floats
  float* Q  = P + 2097152;                         // 2097152 floats
  int*   idx = (int*)(Q + 2097152);                // 655360 ints

  k_xx<<<BATCH * NPTS / 256, 256, 0, stream>>>(x, xx);
  k_pq<<<BATCH * NPTS / 16, 256, 0, stream>>>(x, W, gamma, beta, rmean, rvar, P, Q);
  k_knn<<<dim3(NPTS / 64, BATCH), 256, 0, stream>>>(x, xx, idx);
  k_out<<<dim3(NPTS / 64, BATCH), 256, 0, stream>>>(P, Q, idx, out);
}